// Round 1
// baseline (1426.553 us; speedup 1.0000x reference)
//
#include <hip/hip_runtime.h>
#include <hip/hip_bf16.h>

// Problem constants
#define E_TOTAL 800000
#define NN 50000
#define BM 32           // edges per block tile
#define HID 256

// hT padded stride (floats): 36 keeps 16B alignment and spreads banks (4k+e)%32
#define HT_STRIDE 36
// wtile padded stride (floats): 260 keeps 16B alignment, spreads epilogue banks
#define WT_STRIDE 260

static constexpr float INV_SQRT3_C = 0.57735026918962576f;
// CS = A_SCALAR * (1/16 from fc_w2 scale) * (0.25 final scale)
// A_VECTOR * INV_SQRT3 == A_SCALAR, so the same constant serves out_v.
static constexpr float CS = 0.0013810679320049758f;

typedef __attribute__((address_space(3))) unsigned int lds_u32;
typedef const __attribute__((address_space(1))) unsigned int glb_u32;

__global__ __launch_bounds__(256, 2)
void conv_fused_kernel(const float* __restrict__ nf,     // (NN, 32)
                       const int*   __restrict__ esrc,   // (E,)
                       const int*   __restrict__ edst,   // (E,)
                       const float* __restrict__ esh,    // (E, 4)
                       const float* __restrict__ escal,  // (E, 8)
                       const float* __restrict__ w1,     // (8, 256)
                       const float* __restrict__ w2,     // (256, 256)
                       float* __restrict__ out)          // (NN, 32)
{
    // LDS: hT[256][36] (36 KB) is reused as wtile[32][260] (33.3 KB) after GEMM
    __shared__ float hT[HID * HT_STRIDE];        // 9216 floats
    __shared__ float w2buf[32 * 256];            // 32 KB, k-chunk of fc_w2
    __shared__ float xtile[BM * 32];             // 4 KB gathered node features
    __shared__ float shtile[BM * 4];             // 512 B edge_sh

    const int t  = threadIdx.x;
    const int e0 = blockIdx.x * BM;

    // ---- stage gathered node features: thread -> (edge = t/8, quad = t%8)
    {
        const int e = t >> 3, q = t & 7;
        const int src = esrc[e0 + e];
        const float4 v = *reinterpret_cast<const float4*>(nf + (size_t)src * 32 + q * 4);
        *reinterpret_cast<float4*>(xtile + e * 32 + q * 4) = v;
    }
    if (t < BM) {
        const float4 v = *reinterpret_cast<const float4*>(esh + (size_t)(e0 + t) * 4);
        *reinterpret_cast<float4*>(shtile + t * 4) = v;
    }

    // ---- h-stage: thread t owns hidden unit k = t for all 32 edges
    // h = relu(escal @ w1) * 0.5   (folds 1/sqrt(8) and sqrt(2))
    {
        float w1k[8];
        #pragma unroll
        for (int b = 0; b < 8; ++b) w1k[b] = w1[b * 256 + t];
        #pragma unroll
        for (int e4 = 0; e4 < 8; ++e4) {
            float hv[4];
            #pragma unroll
            for (int ee = 0; ee < 4; ++ee) {
                const float* sp = escal + (size_t)(e0 + e4 * 4 + ee) * 8;  // uniform -> s_load
                float acc = 0.f;
                #pragma unroll
                for (int b = 0; b < 8; ++b) acc = fmaf(sp[b], w1k[b], acc);
                hv[ee] = fmaxf(acc, 0.f) * 0.5f;
            }
            *reinterpret_cast<float4*>(hT + t * HT_STRIDE + e4 * 4) =
                make_float4(hv[0], hv[1], hv[2], hv[3]);
        }
    }
    __syncthreads();

    // ---- fused GEMM: w[32 edges][256] = h[32][256] @ w2[256][256]
    // lane tile: 8 edges x 4 cols. cg = t%64 (col group), eg = t/64 (edge group = wave id)
    const int cg = t & 63;
    const int eg = t >> 6;

    float acc[8][4];
    #pragma unroll
    for (int i = 0; i < 8; ++i)
        #pragma unroll
        for (int j = 0; j < 4; ++j) acc[i][j] = 0.f;

    for (int kc = 0; kc < 8; ++kc) {
        // stage 32 rows of w2 into LDS via async global_load_lds (16B/lane)
        const float* gsrc = w2 + (size_t)kc * 32 * 256;
        #pragma unroll
        for (int r = 0; r < 8; ++r) {
            const int idx = r * 256 + t;   // float4 index; LDS dest = uniform base + lane*16
            __builtin_amdgcn_global_load_lds((glb_u32*)(gsrc + idx * 4),
                                             (lds_u32*)(w2buf + idx * 4),
                                             16, 0, 0);
        }
        __syncthreads();   // drains vmcnt -> chunk resident

        #pragma unroll 4
        for (int kk = 0; kk < 32; ++kk) {
            const int kg = kc * 32 + kk;
            // wave-uniform broadcast reads of h (eg is the wave id)
            const float4 h0 = *reinterpret_cast<const float4*>(hT + kg * HT_STRIDE + eg * 8);
            const float4 h1 = *reinterpret_cast<const float4*>(hT + kg * HT_STRIDE + eg * 8 + 4);
            // contiguous 16B/lane read of w2 row
            const float4 wv = *reinterpret_cast<const float4*>(w2buf + kk * 256 + cg * 4);
            const float hv[8] = {h0.x, h0.y, h0.z, h0.w, h1.x, h1.y, h1.z, h1.w};
            #pragma unroll
            for (int ee = 0; ee < 8; ++ee) {
                acc[ee][0] = fmaf(hv[ee], wv.x, acc[ee][0]);
                acc[ee][1] = fmaf(hv[ee], wv.y, acc[ee][1]);
                acc[ee][2] = fmaf(hv[ee], wv.z, acc[ee][2]);
                acc[ee][3] = fmaf(hv[ee], wv.w, acc[ee][3]);
            }
        }
        __syncthreads();   // all waves done with this chunk before overwrite
    }

    // ---- dump w to LDS (reuse hT region), padded stride for epilogue reads
    float* wtile = hT;
    #pragma unroll
    for (int ee = 0; ee < 8; ++ee) {
        const int e = eg * 8 + ee;
        *reinterpret_cast<float4*>(wtile + e * WT_STRIDE + cg * 4) =
            make_float4(acc[ee][0], acc[ee][1], acc[ee][2], acc[ee][3]);
    }
    __syncthreads();

    // ---- epilogue: thread -> (edge = t/8, out col j = t%8)
    {
        const int e = t >> 3, j = t & 7;
        const float* xr = xtile + e * 32;
        const float  s2  = shtile[e * 4 + 0];
        const float  v20 = shtile[e * 4 + 1];
        const float  v21 = shtile[e * 4 + 2];
        const float  v22 = shtile[e * 4 + 3];
        const float* wr = wtile + e * WT_STRIDE;

        float P0 = 0.f, P1 = 0.f, Q = 0.f, R0 = 0.f, R1 = 0.f, R2 = 0.f;
        #pragma unroll
        for (int u = 0; u < 8; ++u) {
            const float s1 = xr[u];
            const float a0 = xr[8 + u * 3 + 0];
            const float a1 = xr[8 + u * 3 + 1];
            const float a2 = xr[8 + u * 3 + 2];
            const float w0v = wr[u * 8 + j];
            const float w1v = wr[64 + u * 8 + j];
            const float w2v = wr[128 + u * 8 + j];
            const float w3v = wr[192 + u * 8 + j];
            const float dv = a0 * v20 + a1 * v21 + a2 * v22;
            P0 = fmaf(s1, w0v, P0);
            P1 = fmaf(dv, w1v, P1);
            Q  = fmaf(s1, w2v, Q);
            R0 = fmaf(a0, w3v, R0);
            R1 = fmaf(a1, w3v, R1);
            R2 = fmaf(a2, w3v, R2);
        }
        const float os = CS * (s2 * P0 + INV_SQRT3_C * P1);
        const float o0 = CS * (Q * v20 + s2 * R0);
        const float o1 = CS * (Q * v21 + s2 * R1);
        const float o2 = CS * (Q * v22 + s2 * R2);

        const int dst = edst[e0 + e];
        float* op = out + (size_t)dst * 32;
        atomicAdd(op + j, os);
        atomicAdd(op + 8 + j * 3 + 0, o0);
        atomicAdd(op + 8 + j * 3 + 1, o1);
        atomicAdd(op + 8 + j * 3 + 2, o2);
    }
}

extern "C" void kernel_launch(void* const* d_in, const int* in_sizes, int n_in,
                              void* d_out, int out_size, void* d_ws, size_t ws_size,
                              hipStream_t stream) {
    const float* nf    = (const float*)d_in[0];
    const int*   esrc  = (const int*)d_in[1];
    const int*   edst  = (const int*)d_in[2];
    const float* esh   = (const float*)d_in[3];
    const float* escal = (const float*)d_in[4];
    const float* w1    = (const float*)d_in[5];
    const float* w2    = (const float*)d_in[6];
    float* out = (float*)d_out;

    // output is accumulated with atomics -> must zero (harness poisons with 0xAA)
    hipMemsetAsync(d_out, 0, (size_t)out_size * sizeof(float), stream);

    conv_fused_kernel<<<E_TOTAL / BM, 256, 0, stream>>>(
        nf, esrc, edst, esh, escal, w1, w2, out);
}

// Round 3
// 935.079 us; speedup vs baseline: 1.5256x; 1.5256x over previous
//
#include <hip/hip_runtime.h>
#include <hip/hip_bf16.h>

#define E_TOTAL 800000
#define BM 128            // edges per block
#define NKC 16            // K chunks of 16 (K = 256)
#define WT 34             // wtile/xtile stride in floats (2-way banks, 8B aligned)

static constexpr float INV_SQRT3_C = 0.57735026918962576f;
// CS = A_SCALAR * (1/16 fc_w2 scale) * (0.25 final scale); A_VECTOR*INV_SQRT3 == A_SCALAR
static constexpr float CS = 0.0013810679320049758f;

typedef __attribute__((ext_vector_type(8)))  __bf16 bf16x8;
typedef __attribute__((ext_vector_type(8)))  short  s16x8;
typedef __attribute__((ext_vector_type(16))) float  f32x16;

union frag_u { s16x8 s; bf16x8 b; };

typedef __attribute__((address_space(3))) unsigned int lds_u32;
typedef const __attribute__((address_space(1))) unsigned int glb_u32;

__device__ __forceinline__ void split_bf16(float v, short& hi, short& lo) {
    unsigned u  = __float_as_uint(v);
    unsigned hb = (u + 0x7fffu + ((u >> 16) & 1u)) & 0xffff0000u;
    hi = (short)(hb >> 16);
    float r = v - __uint_as_float(hb);           // exact
    unsigned u2 = __float_as_uint(r);
    lo = (short)((u2 + 0x7fffu + ((u2 >> 16) & 1u)) >> 16);
}

// Pre-pass: split fc_w2 (256x256 f32, [k][n]) into fragment-ordered bf16 hi/lo:
// w2f layout [kc(16)][hilo(2)][g(2)][n(256)][i(8)] shorts, k = kc*16 + g*8 + i.
__global__ void split_w2_kernel(const float* __restrict__ w2, short* __restrict__ w2f) {
    const int idx = blockIdx.x * 256 + threadIdx.x;   // 0 .. 131071
    const int i  = idx & 7;
    const int n  = (idx >> 3) & 255;
    const int g  = (idx >> 11) & 1;
    const int hl = (idx >> 12) & 1;
    const int kc = idx >> 13;
    const int k  = kc * 16 + g * 8 + i;
    short hi, lo;
    split_bf16(w2[k * 256 + n], hi, lo);
    w2f[idx] = hl ? lo : hi;
}

__global__ __launch_bounds__(256, 2)
void conv_mfma_kernel(const float* __restrict__ nf,     // (N, 32)
                      const int*   __restrict__ esrc,
                      const int*   __restrict__ edst,
                      const float* __restrict__ esh,    // (E, 4)
                      const float* __restrict__ escal,  // (E, 8)
                      const float* __restrict__ w1,     // (8, 256)
                      const short* __restrict__ w2f,    // frag-ordered hi/lo bf16
                      float* __restrict__ out)          // (N, 32)
{
    __shared__ __align__(16) char smem[54528];
    short* Bbuf  = (short*)smem;               // 2 x 16384 B double buffer
    float* wtile = (float*)smem;               // reused after GEMM: [256][34] f32
    float* xtile = (float*)(smem + 35072);     // [128][34] f32
    float* shtl  = (float*)(smem + 52480);     // [128][4]  f32

    const int t  = threadIdx.x;
    const int l  = t & 63;
    const int wv = t >> 6;                     // wave id = m-tile
    const int e0 = blockIdx.x * BM;

    // ---- stage gathered x and sh for the epilogue (ordered by later barriers)
    {
        const int e = t >> 1, h2 = t & 1;
        const int src = esrc[e0 + e];
        const float* xp = nf + (size_t)src * 32 + h2 * 16;
        float* dp = xtile + e * WT + h2 * 16;
        #pragma unroll
        for (int q = 0; q < 4; ++q) {
            const float4 v4 = *reinterpret_cast<const float4*>(xp + q * 4);
            *reinterpret_cast<float2*>(dp + q * 4)     = make_float2(v4.x, v4.y);
            *reinterpret_cast<float2*>(dp + q * 4 + 2) = make_float2(v4.z, v4.w);
        }
        if (t < BM) {
            const float4 s4 = *reinterpret_cast<const float4*>(esh + (size_t)(e0 + t) * 4);
            *reinterpret_cast<float4*>(shtl + t * 4) = s4;
        }
    }

    // ---- hoist this lane's escal row (edge = m-tile row, lanes 32-63 mirror 0-31)
    const int erow = e0 + wv * 32 + (l & 31);
    float es[8];
    {
        const float4 a = *reinterpret_cast<const float4*>(escal + (size_t)erow * 8);
        const float4 b = *reinterpret_cast<const float4*>(escal + (size_t)erow * 8 + 4);
        es[0]=a.x; es[1]=a.y; es[2]=a.z; es[3]=a.w;
        es[4]=b.x; es[5]=b.y; es[6]=b.z; es[7]=b.w;
    }

    // h = relu(escal @ w1) * 0.5 ; build A-fragment (8 bf16 hi + 8 lo) in-register.
    // lane l: row = l&31, k = kc*16 + (l>>5)*8 + i  (same k-map as B -> any HW
    // k-permutation cancels in the product).
    auto compute_A = [&](int kc, frag_u& fh, frag_u& fl) {
        const int hb = kc * 16 + (l >> 5) * 8;
        float hv[8];
        #pragma unroll
        for (int i2 = 0; i2 < 8; ++i2) hv[i2] = 0.f;
        #pragma unroll
        for (int b = 0; b < 8; ++b) {
            const float4 wa  = *reinterpret_cast<const float4*>(w1 + b * 256 + hb);
            const float4 wb4 = *reinterpret_cast<const float4*>(w1 + b * 256 + hb + 4);
            hv[0] = fmaf(es[b], wa.x,  hv[0]);
            hv[1] = fmaf(es[b], wa.y,  hv[1]);
            hv[2] = fmaf(es[b], wa.z,  hv[2]);
            hv[3] = fmaf(es[b], wa.w,  hv[3]);
            hv[4] = fmaf(es[b], wb4.x, hv[4]);
            hv[5] = fmaf(es[b], wb4.y, hv[5]);
            hv[6] = fmaf(es[b], wb4.z, hv[6]);
            hv[7] = fmaf(es[b], wb4.w, hv[7]);
        }
        #pragma unroll
        for (int i2 = 0; i2 < 8; ++i2) {
            const float v = fmaxf(hv[i2], 0.f) * 0.5f;
            short hi, lo;
            split_bf16(v, hi, lo);
            fh.s[i2] = hi;
            fl.s[i2] = lo;
        }
    };

    auto stage = [&](int kc, int buf) {
        const short* src = w2f + (size_t)kc * 8192;
        short* dst = Bbuf + buf * 8192;
        #pragma unroll
        for (int r = 0; r < 4; ++r) {
            __builtin_amdgcn_global_load_lds((glb_u32*)(src + r * 2048 + t * 8),
                                             (lds_u32*)(dst + r * 2048 + t * 8),
                                             16, 0, 0);
        }
    };

    f32x16 acc[8];
    #pragma unroll
    for (int nt = 0; nt < 8; ++nt)
        #pragma unroll
        for (int q = 0; q < 16; ++q) acc[nt][q] = 0.f;

    stage(0, 0);
    frag_u Ahi, Alo;
    compute_A(0, Ahi, Alo);
    __syncthreads();

    const int bbase = (l >> 5) * 2048 + (l & 31) * 8;   // shorts

    for (int kc = 0; kc < NKC; ++kc) {
        const int cur = kc & 1;
        if (kc + 1 < NKC) stage(kc + 1, cur ^ 1);

        frag_u Anh, Anl;
        if (kc + 1 < NKC) compute_A(kc + 1, Anh, Anl);   // VALU, overlaps MFMA via TLP

        const short* Bb = Bbuf + cur * 8192;
        #pragma unroll
        for (int nt = 0; nt < 8; ++nt) {
            frag_u Bhi, Blo;
            Bhi.s = *reinterpret_cast<const s16x8*>(Bb + bbase + nt * 256);
            Blo.s = *reinterpret_cast<const s16x8*>(Bb + 4096 + bbase + nt * 256);
            acc[nt] = __builtin_amdgcn_mfma_f32_32x32x16_bf16(Ahi.b, Bhi.b, acc[nt], 0, 0, 0);
            acc[nt] = __builtin_amdgcn_mfma_f32_32x32x16_bf16(Alo.b, Bhi.b, acc[nt], 0, 0, 0);
            acc[nt] = __builtin_amdgcn_mfma_f32_32x32x16_bf16(Ahi.b, Blo.b, acc[nt], 0, 0, 0);
        }

        if (kc + 1 < NKC) { Ahi = Anh; Alo = Anl; }
        __syncthreads();   // buf[cur^1] resident (vmcnt drain) + all reads of buf[cur] done
    }

    // ---- epilogue: 4 rounds; wave r dumps its m-tile (transposed, stride 34), all
    // 256 threads contract 32 edges, 4 atomics each.
    const int el = t & 31, j = t >> 5;
    for (int round = 0; round < 4; ++round) {
        if (wv == round) {
            #pragma unroll
            for (int nt = 0; nt < 8; ++nt) {
                float* bp = wtile + (nt * 32 + (l & 31)) * WT + (l >> 5) * 4;
                #pragma unroll
                for (int q = 0; q < 4; ++q) {
                    *reinterpret_cast<float2*>(bp + q * 8)     = make_float2(acc[nt][q*4+0], acc[nt][q*4+1]);
                    *reinterpret_cast<float2*>(bp + q * 8 + 2) = make_float2(acc[nt][q*4+2], acc[nt][q*4+3]);
                }
            }
        }
        __syncthreads();
        {
            const int eg = round * 32 + el;
            const float* xr = xtile + eg * WT;
            const float s2  = shtl[eg * 4 + 0];
            const float v20 = shtl[eg * 4 + 1];
            const float v21 = shtl[eg * 4 + 2];
            const float v22 = shtl[eg * 4 + 3];

            float P0 = 0.f, P1 = 0.f, Q = 0.f, R0 = 0.f, R1 = 0.f, R2 = 0.f;
            #pragma unroll
            for (int u = 0; u < 8; ++u) {
                const float s1 = xr[u];
                const float a0 = xr[8 + u * 3 + 0];
                const float a1 = xr[8 + u * 3 + 1];
                const float a2 = xr[8 + u * 3 + 2];
                const float w0v = wtile[(      u * 8 + j) * WT + el];
                const float w1v = wtile[( 64 + u * 8 + j) * WT + el];
                const float w2v = wtile[(128 + u * 8 + j) * WT + el];
                const float w3v = wtile[(192 + u * 8 + j) * WT + el];
                const float dv = a0 * v20 + a1 * v21 + a2 * v22;
                P0 = fmaf(s1, w0v, P0);
                P1 = fmaf(dv, w1v, P1);
                Q  = fmaf(s1, w2v, Q);
                R0 = fmaf(a0, w3v, R0);
                R1 = fmaf(a1, w3v, R1);
                R2 = fmaf(a2, w3v, R2);
            }
            const float os = CS * (s2 * P0 + INV_SQRT3_C * P1);
            const float o0 = CS * (Q * v20 + s2 * R0);
            const float o1 = CS * (Q * v21 + s2 * R1);
            const float o2 = CS * (Q * v22 + s2 * R2);

            const int dst = edst[e0 + eg];
            float* op = out + (size_t)dst * 32;
            atomicAdd(op + j, os);
            atomicAdd(op + 8 + j * 3 + 0, o0);
            atomicAdd(op + 8 + j * 3 + 1, o1);
            atomicAdd(op + 8 + j * 3 + 2, o2);
        }
        if (round < 3) __syncthreads();   // reads done before next round's dump
    }
}

extern "C" void kernel_launch(void* const* d_in, const int* in_sizes, int n_in,
                              void* d_out, int out_size, void* d_ws, size_t ws_size,
                              hipStream_t stream) {
    const float* nf    = (const float*)d_in[0];
    const int*   esrc  = (const int*)d_in[1];
    const int*   edst  = (const int*)d_in[2];
    const float* esh   = (const float*)d_in[3];
    const float* escal = (const float*)d_in[4];
    const float* w1    = (const float*)d_in[5];
    const float* w2    = (const float*)d_in[6];
    float* out  = (float*)d_out;
    short* w2f  = (short*)d_ws;     // 256 KB

    hipMemsetAsync(d_out, 0, (size_t)out_size * sizeof(float), stream);
    split_w2_kernel<<<512, 256, 0, stream>>>(w2, w2f);
    conv_mfma_kernel<<<E_TOTAL / BM, 256, 0, stream>>>(
        nf, esrc, edst, esh, escal, w1, w2f, out);
}

// Round 4
// 550.156 us; speedup vs baseline: 2.5930x; 1.6997x over previous
//
#include <hip/hip_runtime.h>
#include <hip/hip_bf16.h>

#define E_TOTAL 800000
#define BM 128            // edges per block
#define NKC 16            // K chunks of 16 (K = 256)
#define WT 34             // wtile/xtile stride in floats

static constexpr float INV_SQRT3_C = 0.57735026918962576f;
// CS = A_SCALAR * (1/16 fc_w2 scale) * (0.25 final scale); A_VECTOR*INV_SQRT3 == A_SCALAR
static constexpr float CS = 0.0013810679320049758f;

typedef __attribute__((ext_vector_type(8)))  __bf16 bf16x8;
typedef __attribute__((ext_vector_type(8)))  short  s16x8;
typedef __attribute__((ext_vector_type(16))) float  f32x16;

union frag_u { s16x8 s; bf16x8 b; };

typedef __attribute__((address_space(3))) unsigned int lds_u32;
typedef const __attribute__((address_space(1))) unsigned int glb_u32;

__device__ __forceinline__ void split_bf16(float v, short& hi, short& lo) {
    unsigned u  = __float_as_uint(v);
    unsigned hb = (u + 0x7fffu + ((u >> 16) & 1u)) & 0xffff0000u;
    hi = (short)(hb >> 16);
    float r = v - __uint_as_float(hb);           // exact
    unsigned u2 = __float_as_uint(r);
    lo = (short)((u2 + 0x7fffu + ((u2 >> 16) & 1u)) >> 16);
}

// Pre-pass: split fc_w2 (256x256 f32, [k][n]) into pass-major fragment order:
// w2f[idx] with idx = pass*65536 + kc*4096 + hl*2048 + g*1024 + nloc*8 + i
// where k = kc*16 + g*8 + i, n = pass*128 + nloc, hl picks hi/lo bf16.
__global__ void split_w2_kernel(const float* __restrict__ w2, short* __restrict__ w2f) {
    const int idx  = blockIdx.x * 256 + threadIdx.x;   // 0 .. 131071
    const int i    = idx & 7;
    const int nloc = (idx >> 3) & 127;
    const int g    = (idx >> 10) & 1;
    const int hl   = (idx >> 11) & 1;
    const int kc   = (idx >> 12) & 15;
    const int pass = idx >> 16;
    const int k = kc * 16 + g * 8 + i;
    const int n = pass * 128 + nloc;
    short hi, lo;
    split_bf16(w2[k * 256 + n], hi, lo);
    w2f[idx] = hl ? lo : hi;
}

__global__ __launch_bounds__(256, 3)
void conv_mfma_kernel(const float* __restrict__ nf,     // (N, 32)
                      const int*   __restrict__ esrc,
                      const int*   __restrict__ edst,
                      const float* __restrict__ esh,    // (E, 4)
                      const float* __restrict__ escal,  // (E, 8)
                      const float* __restrict__ w1,     // (8, 256)
                      const short* __restrict__ w2f,    // pass-major frag hi/lo bf16
                      float* __restrict__ out)          // (N, 32)
{
    __shared__ __align__(16) char smem[45056];
    short* Bbuf  = (short*)smem;               // 2 x 4096 shorts (8 KB) double buffer
    float* wtile = (float*)smem;               // reused after K-loop: [128][34] f32
    float* xtile = (float*)(smem + 17408);     // [128][34] f32
    float* shtl  = (float*)(smem + 34816);     // [128][4]  f32
    float* w1l   = (float*)(smem + 36864);     // [8][256]  f32

    const int t  = threadIdx.x;
    const int l  = t & 63;
    const int wv = t >> 6;                     // wave id = 32-edge m-tile
    const int e0 = blockIdx.x * BM;

    // ---- prologue: stage x, sh, w1 into LDS
    {
        const int e = t >> 1, h2 = t & 1;
        const int src = esrc[e0 + e];
        const float* xp = nf + (size_t)src * 32 + h2 * 16;
        float* dp = xtile + e * WT + h2 * 16;
        #pragma unroll
        for (int q = 0; q < 4; ++q) {
            const float4 v4 = *reinterpret_cast<const float4*>(xp + q * 4);
            *reinterpret_cast<float2*>(dp + q * 4)     = make_float2(v4.x, v4.y);
            *reinterpret_cast<float2*>(dp + q * 4 + 2) = make_float2(v4.z, v4.w);
        }
        if (t < BM) {
            const float4 s4 = *reinterpret_cast<const float4*>(esh + (size_t)(e0 + t) * 4);
            *reinterpret_cast<float4*>(shtl + t * 4) = s4;
        }
        *reinterpret_cast<float4*>(w1l + t * 8)     = *reinterpret_cast<const float4*>(w1 + t * 8);
        *reinterpret_cast<float4*>(w1l + t * 8 + 4) = *reinterpret_cast<const float4*>(w1 + t * 8 + 4);
    }

    // ---- hoist this lane's escal row (edge = m-tile row, lanes 32-63 mirror 0-31)
    const int erow = e0 + wv * 32 + (l & 31);
    float es[8];
    {
        const float4 a = *reinterpret_cast<const float4*>(escal + (size_t)erow * 8);
        const float4 b = *reinterpret_cast<const float4*>(escal + (size_t)erow * 8 + 4);
        es[0]=a.x; es[1]=a.y; es[2]=a.z; es[3]=a.w;
        es[4]=b.x; es[5]=b.y; es[6]=b.z; es[7]=b.w;
    }
    __syncthreads();   // w1l / xtile / shtl resident

    // h = relu(escal @ w1) * 0.5 ; A-fragment (8 bf16 hi + 8 lo) in-register.
    // lane l: row = l&31, k = kc*16 + (l>>5)*8 + i  (same k-map as B read).
    auto compute_A = [&](int kc, frag_u& fh, frag_u& fl) {
        const int hb = kc * 16 + (l >> 5) * 8;
        float hv[8];
        #pragma unroll
        for (int i2 = 0; i2 < 8; ++i2) hv[i2] = 0.f;
        #pragma unroll
        for (int b = 0; b < 8; ++b) {
            const float4 wa  = *reinterpret_cast<const float4*>(w1l + b * 256 + hb);
            const float4 wb4 = *reinterpret_cast<const float4*>(w1l + b * 256 + hb + 4);
            hv[0] = fmaf(es[b], wa.x,  hv[0]);
            hv[1] = fmaf(es[b], wa.y,  hv[1]);
            hv[2] = fmaf(es[b], wa.z,  hv[2]);
            hv[3] = fmaf(es[b], wa.w,  hv[3]);
            hv[4] = fmaf(es[b], wb4.x, hv[4]);
            hv[5] = fmaf(es[b], wb4.y, hv[5]);
            hv[6] = fmaf(es[b], wb4.z, hv[6]);
            hv[7] = fmaf(es[b], wb4.w, hv[7]);
        }
        #pragma unroll
        for (int i2 = 0; i2 < 8; ++i2) {
            const float v = fmaxf(hv[i2], 0.f) * 0.5f;
            short hi, lo;
            split_bf16(v, hi, lo);
            fh.s[i2] = hi;
            fl.s[i2] = lo;
        }
    };

    const int el = t >> 3;       // epilogue edge-local (0..31)
    const int j  = t & 7;        // epilogue output column group

    for (int pass = 0; pass < 2; ++pass) {
        const short* wp = w2f + pass * 65536;

        auto stage = [&](int kc, int buf) {
            const short* src = wp + kc * 4096;
            short* dst = Bbuf + buf * 4096;
            #pragma unroll
            for (int r = 0; r < 2; ++r) {
                __builtin_amdgcn_global_load_lds((glb_u32*)(src + r * 2048 + t * 8),
                                                 (lds_u32*)(dst + r * 2048 + t * 8),
                                                 16, 0, 0);
            }
        };

        f32x16 acc[4];
        #pragma unroll
        for (int nt = 0; nt < 4; ++nt)
            #pragma unroll
            for (int q = 0; q < 16; ++q) acc[nt][q] = 0.f;

        stage(0, 0);
        frag_u Ahi, Alo;
        compute_A(0, Ahi, Alo);
        __syncthreads();

        const int bbase = (l >> 5) * 1024 + (l & 31) * 8;   // shorts

        for (int kc = 0; kc < NKC; ++kc) {
            const int cur = kc & 1;
            if (kc + 1 < NKC) stage(kc + 1, cur ^ 1);

            frag_u Anh, Anl;
            if (kc + 1 < NKC) compute_A(kc + 1, Anh, Anl);

            const short* Bb = Bbuf + cur * 4096;
            #pragma unroll
            for (int nt = 0; nt < 4; ++nt) {
                frag_u Bhi, Blo;
                Bhi.s = *reinterpret_cast<const s16x8*>(Bb + bbase + nt * 256);
                Blo.s = *reinterpret_cast<const s16x8*>(Bb + 2048 + bbase + nt * 256);
                acc[nt] = __builtin_amdgcn_mfma_f32_32x32x16_bf16(Ahi.b, Bhi.b, acc[nt], 0, 0, 0);
                acc[nt] = __builtin_amdgcn_mfma_f32_32x32x16_bf16(Alo.b, Bhi.b, acc[nt], 0, 0, 0);
                acc[nt] = __builtin_amdgcn_mfma_f32_32x32x16_bf16(Ahi.b, Blo.b, acc[nt], 0, 0, 0);
            }

            if (kc + 1 < NKC) { Ahi = Anh; Alo = Anl; }
            __syncthreads();   // next buffer resident + all reads of cur done
        }

        // ---- epilogue for this pass (4 rounds; wave r dumps its 32-edge m-tile)
        for (int round = 0; round < 4; ++round) {
            if (wv == round) {
                #pragma unroll
                for (int nt = 0; nt < 4; ++nt) {
                    float* bp = wtile + (nt * 32 + (l & 31)) * WT + (l >> 5) * 4;
                    #pragma unroll
                    for (int q = 0; q < 4; ++q) {
                        *reinterpret_cast<float2*>(bp + q * 8)     = make_float2(acc[nt][q*4+0], acc[nt][q*4+1]);
                        *reinterpret_cast<float2*>(bp + q * 8 + 2) = make_float2(acc[nt][q*4+2], acc[nt][q*4+3]);
                    }
                }
            }
            __syncthreads();

            const int eg = round * 32 + el;
            const float* xr = xtile + eg * WT;
            const float s2  = shtl[eg * 4 + 0];
            const float v20 = shtl[eg * 4 + 1];
            const float v21 = shtl[eg * 4 + 2];
            const float v22 = shtl[eg * 4 + 3];
            const int dst = edst[e0 + eg];
            float* op = out + (size_t)dst * 32;

            if (pass == 0) {
                // cols 0..127 = groups 0 (s1*s2 . w0) and 1 (dv . w1) -> out_s
                float P0 = 0.f, P1 = 0.f;
                #pragma unroll
                for (int u = 0; u < 8; ++u) {
                    const float s1 = xr[u];
                    const float a0 = xr[8 + u * 3 + 0];
                    const float a1 = xr[8 + u * 3 + 1];
                    const float a2 = xr[8 + u * 3 + 2];
                    const float dv = a0 * v20 + a1 * v21 + a2 * v22;
                    P0 = fmaf(s1, wtile[(     u * 8 + j) * WT + el], P0);
                    P1 = fmaf(dv, wtile[(64 + u * 8 + j) * WT + el], P1);
                }
                atomicAdd(op + j, CS * (s2 * P0 + INV_SQRT3_C * P1));
            } else {
                // cols 128..255 = groups 2 (s1 . w2 x v2) and 3 (v1*s2 . w3) -> out_v
                float Q = 0.f, R0 = 0.f, R1 = 0.f, R2 = 0.f;
                #pragma unroll
                for (int u = 0; u < 8; ++u) {
                    const float s1 = xr[u];
                    const float a0 = xr[8 + u * 3 + 0];
                    const float a1 = xr[8 + u * 3 + 1];
                    const float a2 = xr[8 + u * 3 + 2];
                    const float w2v = wtile[(     u * 8 + j) * WT + el];
                    const float w3v = wtile[(64 + u * 8 + j) * WT + el];
                    Q  = fmaf(s1, w2v, Q);
                    R0 = fmaf(a0, w3v, R0);
                    R1 = fmaf(a1, w3v, R1);
                    R2 = fmaf(a2, w3v, R2);
                }
                atomicAdd(op + 8 + j * 3 + 0, CS * (Q * v20 + s2 * R0));
                atomicAdd(op + 8 + j * 3 + 1, CS * (Q * v21 + s2 * R1));
                atomicAdd(op + 8 + j * 3 + 2, CS * (Q * v22 + s2 * R2));
            }
            __syncthreads();   // wtile safe to overwrite (next dump / next pass stage)
        }
    }
}

extern "C" void kernel_launch(void* const* d_in, const int* in_sizes, int n_in,
                              void* d_out, int out_size, void* d_ws, size_t ws_size,
                              hipStream_t stream) {
    const float* nf    = (const float*)d_in[0];
    const int*   esrc  = (const int*)d_in[1];
    const int*   edst  = (const int*)d_in[2];
    const float* esh   = (const float*)d_in[3];
    const float* escal = (const float*)d_in[4];
    const float* w1    = (const float*)d_in[5];
    const float* w2    = (const float*)d_in[6];
    float* out  = (float*)d_out;
    short* w2f  = (short*)d_ws;     // 256 KB

    hipMemsetAsync(d_out, 0, (size_t)out_size * sizeof(float), stream);
    split_w2_kernel<<<512, 256, 0, stream>>>(w2, w2f);
    conv_mfma_kernel<<<E_TOTAL / BM, 256, 0, stream>>>(
        nf, esrc, edst, esh, escal, w1, w2f, out);
}